// Round 7
// baseline (857.802 us; speedup 1.0000x reference)
//
#include <hip/hip_runtime.h>
#include <stdint.h>

// Problem constants
#define B_SZ   32
#define NIN    2312
#define NHID   512
#define NOUT   10
#define T_SZ   350
#define NW32   73                 // ceil(2312/32) bitmask words per input column
#define NW64   8                  // 512/64 ballot words per hidden column
#define NROWP  2336               // NIN padded to 73*32 rows (pad rows never read)

// psp (SRM) kernel eps[n] = CS * n * DS^n, DS = exp(-0.1), CS = e/10
#define DS_D   0.9048374180359595
#define CS_D   0.2718281828459045
#define D100_D 4.5399929762484854e-05   // exp(-10) = DS^100
// refractory recurrence in fp32, exactly like the reference scan
#define DREF_F 0.36787944117144233f     // exp(-1)
#define CREF_F -54.36563656918091f      // -2*10*e

// scan chunking (k4/k6): exact, see round-5 note
#define NCHUNK 7
#define CLEN   50
#define NPF    10

// k3 slice-LDS design
#define C_PB   44                 // columns per block; 256*44 = 11264 >= 11200
#define NBLK3  256
#define SROWS  32                 // rows per slice == bits per mask word
#define NSLICE 73

// ---------------------------------------------------------------------------
// K12: fused bitpack (blocks 0..2335) + W1 transpose (blocks 2336..3503).
__global__ __launch_bounds__(384) void k12(const float* __restrict__ x,
                                           const float* __restrict__ W1,
                                           uint32_t* __restrict__ bits1,
                                           float* __restrict__ W1t) {
    __shared__ float lds[32 * T_SZ];   // 44.8 KB
    const int bid = blockIdx.x;
    const int tid = threadIdx.x;
    if (bid < NW32 * B_SZ) {
        // --- bitpack: block = (b, w); contiguous 32x350 tile -> LDS -> pack
        const int w = bid % NW32;
        const int b = bid / NW32;
        const int rows = (NIN - (w << 5) < 32) ? (NIN - (w << 5)) : 32;
        const float* base = x + ((size_t)(b * NIN + (w << 5))) * T_SZ;
        const int nf2 = rows * (T_SZ / 2);
        for (int f = tid; f < nf2; f += 384)
            ((float2*)lds)[f] = ((const float2*)base)[f];
        __syncthreads();
        if (tid < T_SZ) {
            uint32_t bits = 0;
            for (int j = 0; j < rows; ++j)
                bits |= (lds[j * T_SZ + tid] > 0.5f) ? (1u << j) : 0u;
            bits1[(size_t)(b * T_SZ + tid) * NW32 + w] = bits;
        }
    } else {
        // --- transpose W1 [512, 2312] -> W1t [2336, 512] (pad rows untouched)
        float (*tile)[33] = (float (*)[33])lds;
        const int bb = bid - NW32 * B_SZ;
        const int i0 = (bb % NW32) * 32, o0 = (bb / NW32) * 32;
        const int tx = tid & 31, ty = tid >> 5;  // ty 0..11
#pragma unroll
        for (int r = 0; r < 3; ++r) {
            int row = ty + 12 * r;
            if (row < 32) {
                int o = o0 + row, i = i0 + tx;
                if (i < NIN) tile[row][tx] = W1[(size_t)o * NIN + i];
            }
        }
        __syncthreads();
#pragma unroll
        for (int r = 0; r < 3; ++r) {
            int row = ty + 12 * r;
            if (row < 32) {
                int i = i0 + row, o = o0 + tx;
                if (i < NIN) W1t[(size_t)i * NHID + o] = tile[tx][row];
            }
        }
    }
}

// ---------------------------------------------------------------------------
// K3: slice-LDS dense1. Block owns 44 (b,t)-columns; loops 73 slices of 32
// rows (slice s == bitmask word s), double-buffered 64KB LDS staging from a
// streaming read of W1t; row-uses read float2/thread from LDS (69 TB/s agg
// vs 26 TB/s L2-gather of the previous design). acc[44] float2 in VGPRs.
__global__ __launch_bounds__(256, 1) void k3_dense1(const uint32_t* __restrict__ bits1,
                                                    const float* __restrict__ W1t,
                                                    float* __restrict__ z1ct) {
    __shared__ float sbuf[2][SROWS * NHID];     // 2 x 64 KB
    __shared__ uint32_t cb[C_PB][NSLICE];       // 12.8 KB
    const int tid = threadIdx.x;
    const int c0 = blockIdx.x * C_PB;

    // load bitmask words for my 44 columns (dummy columns -> 0)
    for (int k = tid; k < C_PB * NSLICE; k += 256) {
        int c = k / NSLICE, w = k - c * NSLICE;
        int cg = c0 + c;
        cb[c][w] = (cg < B_SZ * T_SZ) ? bits1[(size_t)cg * NW32 + w] : 0u;
    }

    const float4* G = (const float4*)W1t;       // slice s = G[s*4096 .. +4096)
    float4 stg[16];
#pragma unroll
    for (int k = 0; k < 16; ++k) stg[k] = G[k * 256 + tid];   // slice 0

    float2 acc[C_PB];
#pragma unroll
    for (int c = 0; c < C_PB; ++c) acc[c] = make_float2(0.f, 0.f);

#pragma unroll
    for (int k = 0; k < 16; ++k) ((float4*)sbuf[0])[k * 256 + tid] = stg[k];
    __syncthreads();

    for (int s = 0; s < NSLICE; ++s) {
        const int p = s & 1;
        if (s + 1 < NSLICE) {
#pragma unroll
            for (int k = 0; k < 16; ++k)
                stg[k] = G[(size_t)(s + 1) * 4096 + k * 256 + tid];
        }
        const float2* sp = (const float2*)sbuf[p];
#pragma unroll
        for (int c = 0; c < C_PB; ++c) {
            uint32_t m = cb[c][s];
            while (m) {
                int j = __builtin_ctz(m);
                m &= m - 1;
                float2 v = sp[j * 256 + tid];   // row j of slice, outs 2tid,2tid+1
                acc[c].x += v.x;
                acc[c].y += v.y;
            }
        }
        if (s + 1 < NSLICE) {
#pragma unroll
            for (int k = 0; k < 16; ++k)
                ((float4*)sbuf[p ^ 1])[k * 256 + tid] = stg[k];
        }
        __syncthreads();
    }

    // store: z1ct[(b*8+oc)*350 + t][64], thread covers outputs 2tid, 2tid+1
    const int o = tid * 2;
    const int oc = o >> 6, l6 = o & 63;
#pragma unroll
    for (int c = 0; c < C_PB; ++c) {
        int cg = c0 + c;
        if (cg < B_SZ * T_SZ) {
            int b = cg / T_SZ, t = cg - b * T_SZ;
            *(float2*)(z1ct + ((size_t)(b * NW64 + oc) * T_SZ + t) * 64 + l6) = acc[c];
        }
    }
}

// ---------------------------------------------------------------------------
// K4: fused psp-IIR (fp64 exact truncated FIR) + refractory spike scan (fp32
// = reference recurrence), chunked (7x50, <=100 burn-in, exact).
__global__ __launch_bounds__(64) void k4_fir_scan1(const float* __restrict__ z1ct,
                                                   uint64_t* __restrict__ s1bits) {
    const int lane = threadIdx.x;
    const int bc = blockIdx.x / NCHUNK;   // b*8 + oc
    const int ck = blockIdx.x % NCHUNK;
    const int tstart = ck * CLEN;
    const int tend = tstart + CLEN;
    const int t0 = (tstart >= 100) ? tstart - 100 : 0;
    const float* base = z1ct + (size_t)bc * T_SZ * 64 + lane;
    uint64_t* outp = s1bits + (size_t)bc * T_SZ;
    double A = 0.0, Bs = 0.0, A2 = 0.0, Bs2 = 0.0;
    float ra = 0.0f, rb = 0.0f;
    const double TAIL = D100_D * CS_D;
    float xb[NPF], xdb[NPF];
#pragma unroll
    for (int i = 0; i < NPF; ++i) {
        int t = t0 + i;
        xb[i] = base[(size_t)t * 64];
        int td = t - 100;
        xdb[i] = (td >= 0) ? base[(size_t)td * 64] : 0.0f;
    }
    for (int tb = t0; tb < tend; tb += NPF) {
#pragma unroll
        for (int i = 0; i < NPF; ++i) {
            const int t = tb + i;
            float x = xb[i], xd = xdb[i];
            const int tn = t + NPF;
            xb[i] = (tn < T_SZ) ? base[(size_t)tn * 64] : 0.0f;
            const int td = tn - 100;
            xdb[i] = (td >= 0) ? base[(size_t)td * 64] : 0.0f;
            Bs = DS_D * Bs + DS_D * A;
            A = DS_D * A + (double)x;
            Bs2 = DS_D * Bs2 + DS_D * A2;
            A2 = DS_D * A2 + (double)xd;
            double y = CS_D * Bs - TAIL * (Bs2 + 100.0 * A2);
            float u = (float)y + CREF_F * rb;
            float s = (u >= 10.0f) ? 1.0f : 0.0f;
            float ran = DREF_F * ra + s;
            float rbn = DREF_F * rb + DREF_F * ra;
            ra = ran; rb = rbn;
            uint64_t mball = __ballot(s != 0.0f);
            if (t >= tstart && lane == 0) outp[t] = mball;
        }
    }
}

// ---------------------------------------------------------------------------
// K5: sparse dense2: z2ct[(bo>>6)*350 + t][bo&63] = sum_c s1[b,c,t] * W2[o,c]
__global__ __launch_bounds__(256) void k5_dense2(const uint64_t* __restrict__ s1bits,
                                                 const float* __restrict__ W2,
                                                 float* __restrict__ z2ct) {
    __shared__ float W2s[NHID * NOUT];  // [c][o], 20 KB
    for (int k = threadIdx.x; k < NHID * NOUT; k += 256) {
        int c = k / NOUT, o = k - c * NOUT;
        W2s[k] = W2[(size_t)o * NHID + c];
    }
    __syncthreads();
    int idx = blockIdx.x * 256 + threadIdx.x;   // t*320 + bo
    if (idx >= T_SZ * B_SZ * NOUT) return;
    int t = idx / (B_SZ * NOUT);
    int bo = idx - t * (B_SZ * NOUT);
    int b = bo / NOUT;
    int o = bo - b * NOUT;
    float acc = 0.f;
    const uint64_t* bp = s1bits + (size_t)b * NW64 * T_SZ + t;
#pragma unroll
    for (int wv = 0; wv < NW64; ++wv) {
        uint64_t m = bp[(size_t)wv * T_SZ];
        while (m) {
            int j = __builtin_ctzll(m);
            m &= m - 1;
            acc += W2s[((wv << 6) + j) * NOUT + o];
        }
    }
    z2ct[((size_t)(bo >> 6) * T_SZ + t) * 64 + (bo & 63)] = acc;
}

// ---------------------------------------------------------------------------
// K6: fused psp-IIR + refractory scan, layer 2, chunked. Writes [B, NOUT, T].
__global__ __launch_bounds__(64) void k6_fir_scan2(const float* __restrict__ z2ct,
                                                   float* __restrict__ out) {
    const int lane = threadIdx.x;
    const int g = blockIdx.x / NCHUNK;    // bo group 0..4
    const int ck = blockIdx.x % NCHUNK;
    const int tstart = ck * CLEN;
    const int tend = tstart + CLEN;
    const int t0 = (tstart >= 100) ? tstart - 100 : 0;
    const int bo = (g << 6) + lane;       // 0..319
    const float* base = z2ct + (size_t)g * T_SZ * 64 + lane;
    float* op = out + (size_t)bo * T_SZ;
    double A = 0.0, Bs = 0.0, A2 = 0.0, Bs2 = 0.0;
    float ra = 0.0f, rb = 0.0f;
    const double TAIL = D100_D * CS_D;
    float xb[NPF], xdb[NPF];
#pragma unroll
    for (int i = 0; i < NPF; ++i) {
        int t = t0 + i;
        xb[i] = base[(size_t)t * 64];
        int td = t - 100;
        xdb[i] = (td >= 0) ? base[(size_t)td * 64] : 0.0f;
    }
    for (int tb = t0; tb < tend; tb += NPF) {
#pragma unroll
        for (int i = 0; i < NPF; ++i) {
            const int t = tb + i;
            float x = xb[i], xd = xdb[i];
            const int tn = t + NPF;
            xb[i] = (tn < T_SZ) ? base[(size_t)tn * 64] : 0.0f;
            const int td = tn - 100;
            xdb[i] = (td >= 0) ? base[(size_t)td * 64] : 0.0f;
            Bs = DS_D * Bs + DS_D * A;
            A = DS_D * A + (double)x;
            Bs2 = DS_D * Bs2 + DS_D * A2;
            A2 = DS_D * A2 + (double)xd;
            double y = CS_D * Bs - TAIL * (Bs2 + 100.0 * A2);
            float u = (float)y + CREF_F * rb;
            float s = (u >= 10.0f) ? 1.0f : 0.0f;
            float ran = DREF_F * ra + s;
            float rbn = DREF_F * rb + DREF_F * ra;
            ra = ran; rb = rbn;
            if (t >= tstart) op[t] = s;
        }
    }
}

// ---------------------------------------------------------------------------
extern "C" void kernel_launch(void* const* d_in, const int* in_sizes, int n_in,
                              void* d_out, int out_size, void* d_ws, size_t ws_size,
                              hipStream_t stream) {
    const float* spikeInput = (const float*)d_in[0];  // [32, 2312, 350]
    const float* W1 = (const float*)d_in[1];          // [512, 2312]
    const float* W2 = (const float*)d_in[2];          // [10, 512]
    float* out = (float*)d_out;                       // [32, 10, 350]

    char* ws = (char*)d_ws;
    float* W1t = (float*)(ws + 0);                        //  4,784,128 B (2336 x 512)
    uint32_t* bits1 = (uint32_t*)(ws + 4784128);          //  3,270,400 B
    float* z1ct = (float*)(ws + 8054528);                 // 22,937,600 B
    uint64_t* s1bits = (uint64_t*)(ws + 30992128);        //    716,800 B
    // z2ct aliases bits1's region: bits1 is dead after k3, z2ct written by k5.
    float* z2ct = (float*)(ws + 4784128);                 //    448,000 B (alias)
    // total: 31,708,928 B

    k12<<<NW32 * B_SZ + NW32 * 16, 384, 0, stream>>>(spikeInput, W1, bits1, W1t);
    k3_dense1<<<NBLK3, 256, 0, stream>>>(bits1, W1t, z1ct);
    k4_fir_scan1<<<B_SZ * NW64 * NCHUNK, 64, 0, stream>>>(z1ct, s1bits);
    k5_dense2<<<(T_SZ * B_SZ * NOUT + 255) / 256, 256, 0, stream>>>(s1bits, W2, z2ct);
    k6_fir_scan2<<<5 * NCHUNK, 64, 0, stream>>>(z2ct, out);
}

// Round 8
// 617.587 us; speedup vs baseline: 1.3890x; 1.3890x over previous
//
#include <hip/hip_runtime.h>
#include <stdint.h>

// Problem constants
#define B_SZ   32
#define NIN    2312
#define NHID   512
#define NOUT   10
#define T_SZ   350
#define NW32   73                 // ceil(2312/32) bitmask words per input column
#define NW64   8                  // 512/64 ballot words per hidden column

// psp (SRM) kernel eps[n] = CS * n * DS^n, DS = exp(-0.1), CS = e/10
#define DS_D   0.9048374180359595
#define CS_D   0.2718281828459045
#define D100_D 4.5399929762484854e-05   // exp(-10) = DS^100
// refractory recurrence in fp32, exactly like the reference scan
#define DREF_F 0.36787944117144233f     // exp(-1)
#define CREF_F -54.36563656918091f      // -2*10*e

// scan chunking (k4/k6): exact, see round-5 note
#define NCHUNK 7
#define CLEN   50
#define NPF    10

// k3 slice-LDS design
#define C_PB   44                 // columns per block; 256*44 = 11264 >= 11200
#define NBLK3  256
#define NSLICE 73                 // 73 slices of 32 rows; slice s == mask word s

// ---------------------------------------------------------------------------
// K12: fused bitpack (blocks 0..2335) + W1 transpose (blocks 2336..3503).
__global__ __launch_bounds__(384) void k12(const float* __restrict__ x,
                                           const float* __restrict__ W1,
                                           uint32_t* __restrict__ bits1,
                                           float* __restrict__ W1t) {
    __shared__ float lds[32 * T_SZ];   // 44.8 KB
    const int bid = blockIdx.x;
    const int tid = threadIdx.x;
    if (bid < NW32 * B_SZ) {
        // --- bitpack: block = (b, w); contiguous 32x350 tile -> LDS -> pack
        const int w = bid % NW32;
        const int b = bid / NW32;
        const int rows = (NIN - (w << 5) < 32) ? (NIN - (w << 5)) : 32;
        const float* base = x + ((size_t)(b * NIN + (w << 5))) * T_SZ;
        const int nf2 = rows * (T_SZ / 2);
        for (int f = tid; f < nf2; f += 384)
            ((float2*)lds)[f] = ((const float2*)base)[f];
        __syncthreads();
        if (tid < T_SZ) {
            uint32_t bits = 0;
            for (int j = 0; j < rows; ++j)
                bits |= (lds[j * T_SZ + tid] > 0.5f) ? (1u << j) : 0u;
            bits1[(size_t)(b * T_SZ + tid) * NW32 + w] = bits;
        }
    } else {
        // --- transpose W1 [512, 2312] -> W1t [2336, 512] (pad rows unread:
        //     their mask bits are always 0, so staged garbage is never used)
        float (*tile)[33] = (float (*)[33])lds;
        const int bb = bid - NW32 * B_SZ;
        const int i0 = (bb % NW32) * 32, o0 = (bb / NW32) * 32;
        const int tx = tid & 31, ty = tid >> 5;  // ty 0..11
#pragma unroll
        for (int r = 0; r < 3; ++r) {
            int row = ty + 12 * r;
            if (row < 32) {
                int o = o0 + row, i = i0 + tx;
                if (i < NIN) tile[row][tx] = W1[(size_t)o * NIN + i];
            }
        }
        __syncthreads();
#pragma unroll
        for (int r = 0; r < 3; ++r) {
            int row = ty + 12 * r;
            if (row < 32) {
                int i = i0 + row, o = o0 + tx;
                if (i < NIN) W1t[(size_t)i * NHID + o] = tile[tx][row];
            }
        }
    }
}

// ---------------------------------------------------------------------------
// K3: slice-LDS dense1, round-7 design with the spill fixed:
//  - staging via __builtin_amdgcn_global_load_lds width=16 (no stg[] VGPRs)
//  - acc[44] float2 = 88 VGPRs now fits -> no scratch (R7: WRITE_SIZE 491MB)
__global__ __launch_bounds__(256, 1) void k3_dense1(const uint32_t* __restrict__ bits1,
                                                    const float* __restrict__ W1t,
                                                    float* __restrict__ z1ct) {
    __shared__ float sbuf[2][32 * NHID];        // 2 x 64 KB
    __shared__ uint32_t cb[C_PB][NSLICE];       // 12.8 KB
    const int tid = threadIdx.x;
    const int wv = tid >> 6, lane = tid & 63;
    const int c0 = blockIdx.x * C_PB;

    // bitmask words for my 44 columns (tail columns -> 0 = no compute)
    for (int k = tid; k < C_PB * NSLICE; k += 256) {
        int c = k / NSLICE, w = k - c * NSLICE;
        int cg = c0 + c;
        cb[c][w] = (cg < B_SZ * T_SZ) ? bits1[(size_t)cg * NW32 + w] : 0u;
    }

    // issue slice-0 DMA: 64 chunks of 1 KB; wave wv handles chunks k*4+wv.
    // lds dst is wave-uniform; HW scatters lane i at dst + i*16.
#pragma unroll
    for (int k = 0; k < 16; ++k) {
        const int chunk = k * 4 + wv;
        const float* gp = W1t + (size_t)chunk * 256 + lane * 4;
        __builtin_amdgcn_global_load_lds(
            (const __attribute__((address_space(1))) void*)gp,
            (__attribute__((address_space(3))) void*)&sbuf[0][chunk * 256],
            16, 0, 0);
    }

    float2 acc[C_PB];
#pragma unroll
    for (int c = 0; c < C_PB; ++c) acc[c] = make_float2(0.f, 0.f);

    __syncthreads();   // waits vmcnt(0): slice 0 + cb present

    for (int s = 0; s < NSLICE; ++s) {
        const int p = s & 1;
        if (s + 1 < NSLICE) {
#pragma unroll
            for (int k = 0; k < 16; ++k) {
                const int chunk = k * 4 + wv;
                const float* gp = W1t + (size_t)(s + 1) * 16384 + chunk * 256 + lane * 4;
                __builtin_amdgcn_global_load_lds(
                    (const __attribute__((address_space(1))) void*)gp,
                    (__attribute__((address_space(3))) void*)&sbuf[p ^ 1][chunk * 256],
                    16, 0, 0);
            }
        }
        const float2* sp = (const float2*)sbuf[p];
#pragma unroll
        for (int c = 0; c < C_PB; ++c) {
            uint32_t m = cb[c][s];         // LDS broadcast (same addr all lanes)
            while (m) {
                int j = __builtin_ctz(m);
                m &= m - 1;
                float2 v = sp[j * 256 + tid];   // row j, outputs 2tid, 2tid+1
                acc[c].x += v.x;
                acc[c].y += v.y;
            }
        }
        __syncthreads();   // drains next-slice DMA; protects sbuf[p] reuse
    }

    // store: z1ct[(b*8+oc)*350 + t][64], thread covers outputs 2tid, 2tid+1
    const int o = tid * 2;
    const int oc = o >> 6, l6 = o & 63;
#pragma unroll
    for (int c = 0; c < C_PB; ++c) {
        int cg = c0 + c;
        if (cg < B_SZ * T_SZ) {
            int b = cg / T_SZ, t = cg - b * T_SZ;
            *(float2*)(z1ct + ((size_t)(b * NW64 + oc) * T_SZ + t) * 64 + l6) = acc[c];
        }
    }
}

// ---------------------------------------------------------------------------
// K4: fused psp-IIR (fp64 exact truncated FIR) + refractory spike scan (fp32
// = reference recurrence), chunked (7x50, <=100 burn-in, exact).
__global__ __launch_bounds__(64) void k4_fir_scan1(const float* __restrict__ z1ct,
                                                   uint64_t* __restrict__ s1bits) {
    const int lane = threadIdx.x;
    const int bc = blockIdx.x / NCHUNK;   // b*8 + oc
    const int ck = blockIdx.x % NCHUNK;
    const int tstart = ck * CLEN;
    const int tend = tstart + CLEN;
    const int t0 = (tstart >= 100) ? tstart - 100 : 0;
    const float* base = z1ct + (size_t)bc * T_SZ * 64 + lane;
    uint64_t* outp = s1bits + (size_t)bc * T_SZ;
    double A = 0.0, Bs = 0.0, A2 = 0.0, Bs2 = 0.0;
    float ra = 0.0f, rb = 0.0f;
    const double TAIL = D100_D * CS_D;
    float xb[NPF], xdb[NPF];
#pragma unroll
    for (int i = 0; i < NPF; ++i) {
        int t = t0 + i;
        xb[i] = base[(size_t)t * 64];
        int td = t - 100;
        xdb[i] = (td >= 0) ? base[(size_t)td * 64] : 0.0f;
    }
    for (int tb = t0; tb < tend; tb += NPF) {
#pragma unroll
        for (int i = 0; i < NPF; ++i) {
            const int t = tb + i;
            float x = xb[i], xd = xdb[i];
            const int tn = t + NPF;
            xb[i] = (tn < T_SZ) ? base[(size_t)tn * 64] : 0.0f;
            const int td = tn - 100;
            xdb[i] = (td >= 0) ? base[(size_t)td * 64] : 0.0f;
            Bs = DS_D * Bs + DS_D * A;
            A = DS_D * A + (double)x;
            Bs2 = DS_D * Bs2 + DS_D * A2;
            A2 = DS_D * A2 + (double)xd;
            double y = CS_D * Bs - TAIL * (Bs2 + 100.0 * A2);
            float u = (float)y + CREF_F * rb;
            float s = (u >= 10.0f) ? 1.0f : 0.0f;
            float ran = DREF_F * ra + s;
            float rbn = DREF_F * rb + DREF_F * ra;
            ra = ran; rb = rbn;
            uint64_t mball = __ballot(s != 0.0f);
            if (t >= tstart && lane == 0) outp[t] = mball;
        }
    }
}

// ---------------------------------------------------------------------------
// K5: sparse dense2: z2ct[(bo>>6)*350 + t][bo&63] = sum_c s1[b,c,t] * W2[o,c]
__global__ __launch_bounds__(256) void k5_dense2(const uint64_t* __restrict__ s1bits,
                                                 const float* __restrict__ W2,
                                                 float* __restrict__ z2ct) {
    __shared__ float W2s[NHID * NOUT];  // [c][o], 20 KB
    for (int k = threadIdx.x; k < NHID * NOUT; k += 256) {
        int c = k / NOUT, o = k - c * NOUT;
        W2s[k] = W2[(size_t)o * NHID + c];
    }
    __syncthreads();
    int idx = blockIdx.x * 256 + threadIdx.x;   // t*320 + bo
    if (idx >= T_SZ * B_SZ * NOUT) return;
    int t = idx / (B_SZ * NOUT);
    int bo = idx - t * (B_SZ * NOUT);
    int b = bo / NOUT;
    int o = bo - b * NOUT;
    float acc = 0.f;
    const uint64_t* bp = s1bits + (size_t)b * NW64 * T_SZ + t;
#pragma unroll
    for (int wv = 0; wv < NW64; ++wv) {
        uint64_t m = bp[(size_t)wv * T_SZ];
        while (m) {
            int j = __builtin_ctzll(m);
            m &= m - 1;
            acc += W2s[((wv << 6) + j) * NOUT + o];
        }
    }
    z2ct[((size_t)(bo >> 6) * T_SZ + t) * 64 + (bo & 63)] = acc;
}

// ---------------------------------------------------------------------------
// K6: fused psp-IIR + refractory scan, layer 2, chunked. Writes [B, NOUT, T].
__global__ __launch_bounds__(64) void k6_fir_scan2(const float* __restrict__ z2ct,
                                                   float* __restrict__ out) {
    const int lane = threadIdx.x;
    const int g = blockIdx.x / NCHUNK;    // bo group 0..4
    const int ck = blockIdx.x % NCHUNK;
    const int tstart = ck * CLEN;
    const int tend = tstart + CLEN;
    const int t0 = (tstart >= 100) ? tstart - 100 : 0;
    const int bo = (g << 6) + lane;       // 0..319
    const float* base = z2ct + (size_t)g * T_SZ * 64 + lane;
    float* op = out + (size_t)bo * T_SZ;
    double A = 0.0, Bs = 0.0, A2 = 0.0, Bs2 = 0.0;
    float ra = 0.0f, rb = 0.0f;
    const double TAIL = D100_D * CS_D;
    float xb[NPF], xdb[NPF];
#pragma unroll
    for (int i = 0; i < NPF; ++i) {
        int t = t0 + i;
        xb[i] = base[(size_t)t * 64];
        int td = t - 100;
        xdb[i] = (td >= 0) ? base[(size_t)td * 64] : 0.0f;
    }
    for (int tb = t0; tb < tend; tb += NPF) {
#pragma unroll
        for (int i = 0; i < NPF; ++i) {
            const int t = tb + i;
            float x = xb[i], xd = xdb[i];
            const int tn = t + NPF;
            xb[i] = (tn < T_SZ) ? base[(size_t)tn * 64] : 0.0f;
            const int td = tn - 100;
            xdb[i] = (td >= 0) ? base[(size_t)td * 64] : 0.0f;
            Bs = DS_D * Bs + DS_D * A;
            A = DS_D * A + (double)x;
            Bs2 = DS_D * Bs2 + DS_D * A2;
            A2 = DS_D * A2 + (double)xd;
            double y = CS_D * Bs - TAIL * (Bs2 + 100.0 * A2);
            float u = (float)y + CREF_F * rb;
            float s = (u >= 10.0f) ? 1.0f : 0.0f;
            float ran = DREF_F * ra + s;
            float rbn = DREF_F * rb + DREF_F * ra;
            ra = ran; rb = rbn;
            if (t >= tstart) op[t] = s;
        }
    }
}

// ---------------------------------------------------------------------------
extern "C" void kernel_launch(void* const* d_in, const int* in_sizes, int n_in,
                              void* d_out, int out_size, void* d_ws, size_t ws_size,
                              hipStream_t stream) {
    const float* spikeInput = (const float*)d_in[0];  // [32, 2312, 350]
    const float* W1 = (const float*)d_in[1];          // [512, 2312]
    const float* W2 = (const float*)d_in[2];          // [10, 512]
    float* out = (float*)d_out;                       // [32, 10, 350]

    char* ws = (char*)d_ws;
    float* W1t = (float*)(ws + 0);                        //  4,784,128 B (2336 x 512)
    uint32_t* bits1 = (uint32_t*)(ws + 4784128);          //  3,270,400 B
    float* z1ct = (float*)(ws + 8054528);                 // 22,937,600 B
    uint64_t* s1bits = (uint64_t*)(ws + 30992128);        //    716,800 B
    // z2ct aliases bits1's region: bits1 is dead after k3, z2ct written by k5.
    float* z2ct = (float*)(ws + 4784128);                 //    448,000 B (alias)
    // total: 31,708,928 B

    k12<<<NW32 * B_SZ + NW32 * 16, 384, 0, stream>>>(spikeInput, W1, bits1, W1t);
    k3_dense1<<<NBLK3, 256, 0, stream>>>(bits1, W1t, z1ct);
    k4_fir_scan1<<<B_SZ * NW64 * NCHUNK, 64, 0, stream>>>(z1ct, s1bits);
    k5_dense2<<<(T_SZ * B_SZ * NOUT + 255) / 256, 256, 0, stream>>>(s1bits, W2, z2ct);
    k6_fir_scan2<<<5 * NCHUNK, 64, 0, stream>>>(z2ct, out);
}

// Round 9
// 359.502 us; speedup vs baseline: 2.3861x; 1.7179x over previous
//
#include <hip/hip_runtime.h>
#include <stdint.h>

// Problem constants
#define B_SZ   32
#define NIN    2312
#define NHID   512
#define NOUT   10
#define T_SZ   350
#define NW32   73                 // ceil(2312/32) bitmask words per input column
#define NW64   8                  // 512/64 ballot words per hidden column

// psp (SRM) kernel eps[n] = CS * n * DS^n, DS = exp(-0.1), CS = e/10
#define DS_D   0.9048374180359595
#define CS_D   0.2718281828459045
#define D100_D 4.5399929762484854e-05   // exp(-10) = DS^100
// refractory recurrence in fp32, exactly like the reference scan
#define DREF_F 0.36787944117144233f     // exp(-1)
#define CREF_F -54.36563656918091f      // -2*10*e

// scan chunking (k4/k6): exact, see round-5 note
#define NCHUNK 7
#define CLEN   50
#define NPF    10

// k3 slice-LDS design
#define C_PB   44                 // columns per block; 256*44 = 11264 >= 11200
#define NBLK3  256
#define NSLICE 73                 // 73 slices of 32 rows; slice s == mask word s

// ---------------------------------------------------------------------------
// K12: fused bitpack (blocks 0..2335) + W1 transpose (blocks 2336..3503).
__global__ __launch_bounds__(384) void k12(const float* __restrict__ x,
                                           const float* __restrict__ W1,
                                           uint32_t* __restrict__ bits1,
                                           float* __restrict__ W1t) {
    __shared__ float lds[32 * T_SZ];   // 44.8 KB
    const int bid = blockIdx.x;
    const int tid = threadIdx.x;
    if (bid < NW32 * B_SZ) {
        // --- bitpack: block = (b, w); contiguous 32x350 tile -> LDS -> pack
        const int w = bid % NW32;
        const int b = bid / NW32;
        const int rows = (NIN - (w << 5) < 32) ? (NIN - (w << 5)) : 32;
        const float* base = x + ((size_t)(b * NIN + (w << 5))) * T_SZ;
        const int nf2 = rows * (T_SZ / 2);
        for (int f = tid; f < nf2; f += 384)
            ((float2*)lds)[f] = ((const float2*)base)[f];
        __syncthreads();
        if (tid < T_SZ) {
            uint32_t bits = 0;
            for (int j = 0; j < rows; ++j)
                bits |= (lds[j * T_SZ + tid] > 0.5f) ? (1u << j) : 0u;
            bits1[(size_t)(b * T_SZ + tid) * NW32 + w] = bits;
        }
    } else {
        // --- transpose W1 [512, 2312] -> W1t [2336, 512] (pad rows unread:
        //     their mask bits are always 0, so staged garbage is never used)
        float (*tile)[33] = (float (*)[33])lds;
        const int bb = bid - NW32 * B_SZ;
        const int i0 = (bb % NW32) * 32, o0 = (bb / NW32) * 32;
        const int tx = tid & 31, ty = tid >> 5;  // ty 0..11
#pragma unroll
        for (int r = 0; r < 3; ++r) {
            int row = ty + 12 * r;
            if (row < 32) {
                int o = o0 + row, i = i0 + tx;
                if (i < NIN) tile[row][tx] = W1[(size_t)o * NIN + i];
            }
        }
        __syncthreads();
#pragma unroll
        for (int r = 0; r < 3; ++r) {
            int row = ty + 12 * r;
            if (row < 32) {
                int i = i0 + row, o = o0 + tx;
                if (i < NIN) W1t[(size_t)i * NHID + o] = tile[tx][row];
            }
        }
    }
}

// ---------------------------------------------------------------------------
// K3: slice-LDS dense1, round-8 design with the latency exposure fixed:
// R8 ran 4 waves/CU (1/SIMD) -> dependent ds_read chains fully exposed
// (VALUBusy 10%, 5.3us/slice). Now 1024 threads = 16 waves = 4 waves/SIMD.
// 8 groups of 128 threads; group g covers columns c = g, g+8, ... (5-6 of
// 44); each thread owns 4 outputs (float4 ds_read_b128, best bytes/issue).
// Staging still via global_load_lds width=16 (no VGPR staging, no spill).
__global__ __launch_bounds__(1024, 1) void k3_dense1(const uint32_t* __restrict__ bits1,
                                                     const float* __restrict__ W1t,
                                                     float* __restrict__ z1ct) {
    __shared__ float sbuf[2][32 * NHID];        // 2 x 64 KB
    __shared__ uint32_t cb[C_PB][NSLICE];       // 12.8 KB
    const int tid = threadIdx.x;
    const int wv = tid >> 6;                    // wave 0..15
    const int lane = tid & 63;
    const int g = tid >> 7;                     // group 0..7
    const int l128 = tid & 127;                 // lane within group
    const int c0 = blockIdx.x * C_PB;

    // bitmask words for my 44 columns (tail columns -> 0 = no compute)
    for (int k = tid; k < C_PB * NSLICE; k += 1024) {
        int c = k / NSLICE, w = k - c * NSLICE;
        int cg = c0 + c;
        cb[c][w] = (cg < B_SZ * T_SZ) ? bits1[(size_t)cg * NW32 + w] : 0u;
    }

    // slice-0 DMA: 64 chunks of 1 KB; wave wv handles chunks wv*4+k.
#pragma unroll
    for (int k = 0; k < 4; ++k) {
        const int chunk = wv * 4 + k;
        const float* gp = W1t + (size_t)chunk * 256 + lane * 4;
        __builtin_amdgcn_global_load_lds(
            (const __attribute__((address_space(1))) void*)gp,
            (__attribute__((address_space(3))) void*)&sbuf[0][chunk * 256],
            16, 0, 0);
    }

    float4 acc[6];
#pragma unroll
    for (int k = 0; k < 6; ++k) acc[k] = make_float4(0.f, 0.f, 0.f, 0.f);

    __syncthreads();   // drains vmcnt: slice 0 + cb present

    for (int s = 0; s < NSLICE; ++s) {
        const int p = s & 1;
        if (s + 1 < NSLICE) {
#pragma unroll
            for (int k = 0; k < 4; ++k) {
                const int chunk = wv * 4 + k;
                const float* gp = W1t + (size_t)(s + 1) * 16384 + chunk * 256 + lane * 4;
                __builtin_amdgcn_global_load_lds(
                    (const __attribute__((address_space(1))) void*)gp,
                    (__attribute__((address_space(3))) void*)&sbuf[p ^ 1][chunk * 256],
                    16, 0, 0);
            }
        }
        const float4* sp = (const float4*)sbuf[p];
        // 6 independent accumulation chains (columns g, g+8, ..., g+40)
#pragma unroll
        for (int k = 0; k < 6; ++k) {
            const int c = g + 8 * k;
            if (c < C_PB) {
                uint32_t m = cb[c][s];      // LDS broadcast within each wave
                while (m) {
                    int j = __builtin_ctz(m);
                    m &= m - 1;
                    float4 v = sp[j * 128 + l128];  // row j, outs 4*l128..+3
                    acc[k].x += v.x; acc[k].y += v.y;
                    acc[k].z += v.z; acc[k].w += v.w;
                }
            }
        }
        __syncthreads();   // drains next-slice DMA; protects sbuf[p] reuse
    }

    // store: z1ct[(b*8+oc)*350 + t][64]; thread owns outputs 4*l128..+3
    const int o = l128 * 4;
    const int oc = o >> 6, l6 = o & 63;
#pragma unroll
    for (int k = 0; k < 6; ++k) {
        const int c = g + 8 * k;
        if (c < C_PB) {
            int cg = c0 + c;
            if (cg < B_SZ * T_SZ) {
                int b = cg / T_SZ, t = cg - b * T_SZ;
                *(float4*)(z1ct + ((size_t)(b * NW64 + oc) * T_SZ + t) * 64 + l6) = acc[k];
            }
        }
    }
}

// ---------------------------------------------------------------------------
// K4: fused psp-IIR (fp64 exact truncated FIR) + refractory spike scan (fp32
// = reference recurrence), chunked (7x50, <=100 burn-in, exact).
__global__ __launch_bounds__(64) void k4_fir_scan1(const float* __restrict__ z1ct,
                                                   uint64_t* __restrict__ s1bits) {
    const int lane = threadIdx.x;
    const int bc = blockIdx.x / NCHUNK;   // b*8 + oc
    const int ck = blockIdx.x % NCHUNK;
    const int tstart = ck * CLEN;
    const int tend = tstart + CLEN;
    const int t0 = (tstart >= 100) ? tstart - 100 : 0;
    const float* base = z1ct + (size_t)bc * T_SZ * 64 + lane;
    uint64_t* outp = s1bits + (size_t)bc * T_SZ;
    double A = 0.0, Bs = 0.0, A2 = 0.0, Bs2 = 0.0;
    float ra = 0.0f, rb = 0.0f;
    const double TAIL = D100_D * CS_D;
    float xb[NPF], xdb[NPF];
#pragma unroll
    for (int i = 0; i < NPF; ++i) {
        int t = t0 + i;
        xb[i] = base[(size_t)t * 64];
        int td = t - 100;
        xdb[i] = (td >= 0) ? base[(size_t)td * 64] : 0.0f;
    }
    for (int tb = t0; tb < tend; tb += NPF) {
#pragma unroll
        for (int i = 0; i < NPF; ++i) {
            const int t = tb + i;
            float x = xb[i], xd = xdb[i];
            const int tn = t + NPF;
            xb[i] = (tn < T_SZ) ? base[(size_t)tn * 64] : 0.0f;
            const int td = tn - 100;
            xdb[i] = (td >= 0) ? base[(size_t)td * 64] : 0.0f;
            Bs = DS_D * Bs + DS_D * A;
            A = DS_D * A + (double)x;
            Bs2 = DS_D * Bs2 + DS_D * A2;
            A2 = DS_D * A2 + (double)xd;
            double y = CS_D * Bs - TAIL * (Bs2 + 100.0 * A2);
            float u = (float)y + CREF_F * rb;
            float s = (u >= 10.0f) ? 1.0f : 0.0f;
            float ran = DREF_F * ra + s;
            float rbn = DREF_F * rb + DREF_F * ra;
            ra = ran; rb = rbn;
            uint64_t mball = __ballot(s != 0.0f);
            if (t >= tstart && lane == 0) outp[t] = mball;
        }
    }
}

// ---------------------------------------------------------------------------
// K5: sparse dense2: z2ct[(bo>>6)*350 + t][bo&63] = sum_c s1[b,c,t] * W2[o,c]
__global__ __launch_bounds__(256) void k5_dense2(const uint64_t* __restrict__ s1bits,
                                                 const float* __restrict__ W2,
                                                 float* __restrict__ z2ct) {
    __shared__ float W2s[NHID * NOUT];  // [c][o], 20 KB
    for (int k = threadIdx.x; k < NHID * NOUT; k += 256) {
        int c = k / NOUT, o = k - c * NOUT;
        W2s[k] = W2[(size_t)o * NHID + c];
    }
    __syncthreads();
    int idx = blockIdx.x * 256 + threadIdx.x;   // t*320 + bo
    if (idx >= T_SZ * B_SZ * NOUT) return;
    int t = idx / (B_SZ * NOUT);
    int bo = idx - t * (B_SZ * NOUT);
    int b = bo / NOUT;
    int o = bo - b * NOUT;
    float acc = 0.f;
    const uint64_t* bp = s1bits + (size_t)b * NW64 * T_SZ + t;
#pragma unroll
    for (int wv = 0; wv < NW64; ++wv) {
        uint64_t m = bp[(size_t)wv * T_SZ];
        while (m) {
            int j = __builtin_ctzll(m);
            m &= m - 1;
            acc += W2s[((wv << 6) + j) * NOUT + o];
        }
    }
    z2ct[((size_t)(bo >> 6) * T_SZ + t) * 64 + (bo & 63)] = acc;
}

// ---------------------------------------------------------------------------
// K6: fused psp-IIR + refractory scan, layer 2, chunked. Writes [B, NOUT, T].
__global__ __launch_bounds__(64) void k6_fir_scan2(const float* __restrict__ z2ct,
                                                   float* __restrict__ out) {
    const int lane = threadIdx.x;
    const int g = blockIdx.x / NCHUNK;    // bo group 0..4
    const int ck = blockIdx.x % NCHUNK;
    const int tstart = ck * CLEN;
    const int tend = tstart + CLEN;
    const int t0 = (tstart >= 100) ? tstart - 100 : 0;
    const int bo = (g << 6) + lane;       // 0..319
    const float* base = z2ct + (size_t)g * T_SZ * 64 + lane;
    float* op = out + (size_t)bo * T_SZ;
    double A = 0.0, Bs = 0.0, A2 = 0.0, Bs2 = 0.0;
    float ra = 0.0f, rb = 0.0f;
    const double TAIL = D100_D * CS_D;
    float xb[NPF], xdb[NPF];
#pragma unroll
    for (int i = 0; i < NPF; ++i) {
        int t = t0 + i;
        xb[i] = base[(size_t)t * 64];
        int td = t - 100;
        xdb[i] = (td >= 0) ? base[(size_t)td * 64] : 0.0f;
    }
    for (int tb = t0; tb < tend; tb += NPF) {
#pragma unroll
        for (int i = 0; i < NPF; ++i) {
            const int t = tb + i;
            float x = xb[i], xd = xdb[i];
            const int tn = t + NPF;
            xb[i] = (tn < T_SZ) ? base[(size_t)tn * 64] : 0.0f;
            const int td = tn - 100;
            xdb[i] = (td >= 0) ? base[(size_t)td * 64] : 0.0f;
            Bs = DS_D * Bs + DS_D * A;
            A = DS_D * A + (double)x;
            Bs2 = DS_D * Bs2 + DS_D * A2;
            A2 = DS_D * A2 + (double)xd;
            double y = CS_D * Bs - TAIL * (Bs2 + 100.0 * A2);
            float u = (float)y + CREF_F * rb;
            float s = (u >= 10.0f) ? 1.0f : 0.0f;
            float ran = DREF_F * ra + s;
            float rbn = DREF_F * rb + DREF_F * ra;
            ra = ran; rb = rbn;
            if (t >= tstart) op[t] = s;
        }
    }
}

// ---------------------------------------------------------------------------
extern "C" void kernel_launch(void* const* d_in, const int* in_sizes, int n_in,
                              void* d_out, int out_size, void* d_ws, size_t ws_size,
                              hipStream_t stream) {
    const float* spikeInput = (const float*)d_in[0];  // [32, 2312, 350]
    const float* W1 = (const float*)d_in[1];          // [512, 2312]
    const float* W2 = (const float*)d_in[2];          // [10, 512]
    float* out = (float*)d_out;                       // [32, 10, 350]

    char* ws = (char*)d_ws;
    float* W1t = (float*)(ws + 0);                        //  4,784,128 B (2336 x 512)
    uint32_t* bits1 = (uint32_t*)(ws + 4784128);          //  3,270,400 B
    float* z1ct = (float*)(ws + 8054528);                 // 22,937,600 B
    uint64_t* s1bits = (uint64_t*)(ws + 30992128);        //    716,800 B
    // z2ct aliases bits1's region: bits1 is dead after k3, z2ct written by k5.
    float* z2ct = (float*)(ws + 4784128);                 //    448,000 B (alias)
    // total: 31,708,928 B

    k12<<<NW32 * B_SZ + NW32 * 16, 384, 0, stream>>>(spikeInput, W1, bits1, W1t);
    k3_dense1<<<NBLK3, 1024, 0, stream>>>(bits1, W1t, z1ct);
    k4_fir_scan1<<<B_SZ * NW64 * NCHUNK, 64, 0, stream>>>(z1ct, s1bits);
    k5_dense2<<<(T_SZ * B_SZ * NOUT + 255) / 256, 256, 0, stream>>>(s1bits, W2, z2ct);
    k6_fir_scan2<<<5 * NCHUNK, 64, 0, stream>>>(z2ct, out);
}

// Round 10
// 317.814 us; speedup vs baseline: 2.6991x; 1.1312x over previous
//
#include <hip/hip_runtime.h>
#include <stdint.h>

// Problem constants
#define B_SZ   32
#define NIN    2312
#define NHID   512
#define NOUT   10
#define T_SZ   350
#define NW32   73                 // ceil(2312/32) bitmask words per input column
#define NW64   8                  // 512/64 ballot words per hidden column
#define NHALF  256                // output half-width for L2-resident W1
#define NROW   2313               // NIN + 1 dummy zero row (branch-free padding)

// psp (SRM) kernel eps[n] = CS * n * DS^n, DS = exp(-0.1), CS = e/10
#define DS_D   0.9048374180359595
#define CS_D   0.2718281828459045
#define D100_D 4.5399929762484854e-05   // exp(-10) = DS^100
// refractory recurrence in fp32, exactly like the reference scan
#define DREF_F 0.36787944117144233f     // exp(-1)
#define CREF_F -54.36563656918091f      // -2*10*e

// scan chunking (k45/k6): 7 chunks of 50; psp-IIR warm-started <=100 steps
// early is EXACT (FIR truncated at 100 taps); refractory burn-in error decays
// e^-n -> < 1e-28 by chunk start (absorbed below fp32 ulp).
#define NCHUNK 7
#define CLEN   50
#define NPF    10                 // ring depth; 50/100/150 all %10==0

// ---------------------------------------------------------------------------
// K12: fused bitpack (blocks 0..2335) + W1 half-split pack (2336..3503) +
//      dummy-zero-row fill (block 3504). Bitpack now float4 streaming.
__global__ __launch_bounds__(384) void k12(const float* __restrict__ x,
                                           const float* __restrict__ W1,
                                           uint32_t* __restrict__ bits1,
                                           float* __restrict__ W1s) {
    __shared__ float lds[32 * T_SZ];   // 44.8 KB
    const int bid = blockIdx.x;
    const int tid = threadIdx.x;
    if (bid < NW32 * B_SZ) {
        // --- bitpack: block = (b, w); contiguous rowsx350 tile -> LDS -> pack
        const int w = bid % NW32;
        const int b = bid / NW32;
        const int rows = (NIN - (w << 5) < 32) ? (NIN - (w << 5)) : 32;  // 32 or 8
        const float* base = x + ((size_t)(b * NIN + (w << 5))) * T_SZ;
        const int nf4 = (rows * T_SZ) >> 2;     // rows even -> divisible by 4
        for (int f = tid; f < nf4; f += 384)
            ((float4*)lds)[f] = ((const float4*)base)[f];
        __syncthreads();
        if (tid < T_SZ) {
            uint32_t bits = 0;
            for (int j = 0; j < rows; ++j)
                bits |= (lds[j * T_SZ + tid] > 0.5f) ? (1u << j) : 0u;
            bits1[(size_t)(b * T_SZ + tid) * NW32 + w] = bits;
        }
    } else if (bid < NW32 * B_SZ + NW32 * 16) {
        // --- pack W1 [512, 2312] -> W1s[h][i][256], h = o>>8
        float (*tile)[33] = (float (*)[33])lds;
        const int bb = bid - NW32 * B_SZ;
        const int i0 = (bb % NW32) * 32, o0 = (bb / NW32) * 32;
        const int tx = tid & 31, ty = tid >> 5;  // ty 0..11
#pragma unroll
        for (int r = 0; r < 3; ++r) {
            int row = ty + 12 * r;
            if (row < 32) {
                int o = o0 + row, i = i0 + tx;
                if (i < NIN) tile[row][tx] = W1[(size_t)o * NIN + i];
            }
        }
        __syncthreads();
#pragma unroll
        for (int r = 0; r < 3; ++r) {
            int row = ty + 12 * r;
            if (row < 32) {
                int i = i0 + row, o = o0 + tx;
                if (i < NIN)
                    W1s[((size_t)(o >> 8) * NROW + i) * NHALF + (o & 255)] = tile[tx][row];
            }
        }
    } else {
        // --- dummy zero row i = NIN for both halves
        if (tid < NHALF) {
            W1s[((size_t)0 * NROW + NIN) * NHALF + tid] = 0.0f;
            W1s[((size_t)1 * NROW + NIN) * NHALF + tid] = 0.0f;
        }
    }
}

// ---------------------------------------------------------------------------
// K3: sparse dense1 (R6 gather form, proven 101us / 26.3 TB/s L2-gather).
// Half-split for L2 residency; single-wave shfl prefix scan; branch-free
// 4-deep pipelined row loop via dummy zero-row padding.
__global__ __launch_bounds__(256) void k3_dense1(const uint32_t* __restrict__ bits1,
                                                 const float* __restrict__ W1s,
                                                 float* __restrict__ z1ct) {
    __shared__ uint32_t words[128];
    __shared__ uint16_t pfx[80];
    __shared__ uint16_t idxbuf[NIN + 16];
    __shared__ float red[3][NHALF];
    __shared__ float fin[NHALF];

    const int bt = blockIdx.x;          // b*350 + t
    const int h = blockIdx.y;           // 0 or 1
    const int tid = threadIdx.x;
    const int wv = tid >> 6, lane = tid & 63;

    if (tid < 128) words[tid] = (tid < NW32) ? bits1[(size_t)bt * NW32 + tid] : 0u;
    __syncthreads();

    if (wv == 0) {
        uint32_t w0 = words[lane];
        uint32_t w1 = words[lane + 64];
        int p0 = __popc(w0), p1 = __popc(w1);
        int s0 = p0, s1 = p1;
#pragma unroll
        for (int off = 1; off < 64; off <<= 1) {
            int u0 = __shfl_up(s0, off);
            int u1 = __shfl_up(s1, off);
            if (lane >= off) { s0 += u0; s1 += u1; }
        }
        int tot0 = __shfl(s0, 63);
        pfx[lane] = (uint16_t)(s0 - p0);
        if (lane < 9) pfx[lane + 64] = (uint16_t)(tot0 + s1 - p1);
        if (lane == 8) pfx[73] = (uint16_t)(tot0 + s1);   // ntot
    }
    __syncthreads();

    const int ntot = pfx[73];
    const int npad = (ntot + 15) & ~15;
    if (tid < NW32) {
        uint32_t m = words[tid];
        int p = pfx[tid];
        while (m) {
            int j = __builtin_ctz(m);
            m &= m - 1;
            idxbuf[p++] = (uint16_t)((tid << 5) + j);
        }
    }
    if (tid >= 240) {                   // pad to multiple of 16 with zero row
        int k = tid - 240;
        if (ntot + k < npad) idxbuf[ntot + k] = (uint16_t)NIN;
    }
    __syncthreads();

    const float* Wh = W1s + (size_t)h * NROW * NHALF;
    float4 acc = make_float4(0.f, 0.f, 0.f, 0.f);
    for (int r = wv; r < npad; r += 16) {
        int i0 = idxbuf[r], i1 = idxbuf[r + 4], i2 = idxbuf[r + 8], i3 = idxbuf[r + 12];
        float4 v0 = ((const float4*)(Wh + (size_t)i0 * NHALF))[lane];
        float4 v1 = ((const float4*)(Wh + (size_t)i1 * NHALF))[lane];
        float4 v2 = ((const float4*)(Wh + (size_t)i2 * NHALF))[lane];
        float4 v3 = ((const float4*)(Wh + (size_t)i3 * NHALF))[lane];
        acc.x += v0.x; acc.y += v0.y; acc.z += v0.z; acc.w += v0.w;
        acc.x += v1.x; acc.y += v1.y; acc.z += v1.z; acc.w += v1.w;
        acc.x += v2.x; acc.y += v2.y; acc.z += v2.z; acc.w += v2.w;
        acc.x += v3.x; acc.y += v3.y; acc.z += v3.z; acc.w += v3.w;
    }
    if (wv > 0) ((float4*)red[wv - 1])[lane] = acc;
    __syncthreads();
    if (wv == 0) {
        float4 a1 = ((float4*)red[0])[lane];
        float4 a2 = ((float4*)red[1])[lane];
        float4 a3 = ((float4*)red[2])[lane];
        acc.x = ((acc.x + a1.x) + a2.x) + a3.x;
        acc.y = ((acc.y + a1.y) + a2.y) + a3.y;
        acc.z = ((acc.z + a1.z) + a2.z) + a3.z;
        acc.w = ((acc.w + a1.w) + a2.w) + a3.w;
        ((float4*)fin)[lane] = acc;
    }
    __syncthreads();
    const int och = (h << 8) + tid;
    const int oc = och >> 6, l6 = och & 63;
    const int b = bt / T_SZ, t = bt - b * T_SZ;
    z1ct[((size_t)(b * NW64 + oc) * T_SZ + t) * 64 + l6] = fin[tid];
}

// ---------------------------------------------------------------------------
// K45: fused layer-1 scan + dense2. Block = (b, chunk), 512 threads = 8 waves;
// wave wv scans channels wv*64..+63 (identical chunked IIR arithmetic to the
// old k4), ballots into LDS (no global s1bits round-trip); then 500 (t,o)
// pairs compute z2 with the same wv-ascending/ctz-ascending sum order as the
// old k5 (bit-identical result).
__global__ __launch_bounds__(512) void k45(const float* __restrict__ z1ct,
                                           const float* __restrict__ W2,
                                           float* __restrict__ z2ct) {
    __shared__ float W2s[NHID * NOUT];      // [c][o], 20 KB
    __shared__ uint64_t sw[CLEN][NW64];     // s1 ballot words for my 50 t's
    const int tid = threadIdx.x;
    const int wv = tid >> 6, lane = tid & 63;
    const int b = blockIdx.x / NCHUNK;
    const int ck = blockIdx.x % NCHUNK;
    const int tstart = ck * CLEN;
    const int tend = tstart + CLEN;
    const int t0 = (tstart >= 100) ? tstart - 100 : 0;

    for (int k = tid; k < NHID * NOUT; k += 512) {
        int c = k / NOUT, o = k - c * NOUT;
        W2s[k] = W2[(size_t)o * NHID + c];
    }

    // ---- layer-1 chunked scan (identical math to old k4)
    const float* base = z1ct + (size_t)(b * NW64 + wv) * T_SZ * 64 + lane;
    double A = 0.0, Bs = 0.0, A2 = 0.0, Bs2 = 0.0;
    float ra = 0.0f, rb = 0.0f;
    const double TAIL = D100_D * CS_D;
    float xb[NPF], xdb[NPF];
#pragma unroll
    for (int i = 0; i < NPF; ++i) {
        int t = t0 + i;
        xb[i] = base[(size_t)t * 64];
        int td = t - 100;
        xdb[i] = (td >= 0) ? base[(size_t)td * 64] : 0.0f;
    }
    for (int tb = t0; tb < tend; tb += NPF) {
#pragma unroll
        for (int i = 0; i < NPF; ++i) {
            const int t = tb + i;
            float x = xb[i], xd = xdb[i];
            const int tn = t + NPF;
            xb[i] = (tn < T_SZ) ? base[(size_t)tn * 64] : 0.0f;
            const int td = tn - 100;
            xdb[i] = (td >= 0) ? base[(size_t)td * 64] : 0.0f;
            Bs = DS_D * Bs + DS_D * A;
            A = DS_D * A + (double)x;
            Bs2 = DS_D * Bs2 + DS_D * A2;
            A2 = DS_D * A2 + (double)xd;
            double y = CS_D * Bs - TAIL * (Bs2 + 100.0 * A2);
            float u = (float)y + CREF_F * rb;
            float s = (u >= 10.0f) ? 1.0f : 0.0f;
            float ran = DREF_F * ra + s;
            float rbn = DREF_F * rb + DREF_F * ra;
            ra = ran; rb = rbn;
            uint64_t mball = __ballot(s != 0.0f);
            if (t >= tstart && lane == 0) sw[t - tstart][wv] = mball;
        }
    }
    __syncthreads();

    // ---- dense2 for my 50 t's (same order as old k5 -> bit-identical)
    if (tid < CLEN * NOUT) {                // 500 of 512
        const int tr = tid / NOUT;
        const int o = tid - tr * NOUT;
        const int t = tstart + tr;
        float acc = 0.f;
#pragma unroll
        for (int w2 = 0; w2 < NW64; ++w2) {
            uint64_t m = sw[tr][w2];
            while (m) {
                int j = __builtin_ctzll(m);
                m &= m - 1;
                acc += W2s[((w2 << 6) + j) * NOUT + o];
            }
        }
        const int bo = b * NOUT + o;
        z2ct[((size_t)(bo >> 6) * T_SZ + t) * 64 + (bo & 63)] = acc;
    }
}

// ---------------------------------------------------------------------------
// K6: fused psp-IIR + refractory scan, layer 2, chunked. Writes [B, NOUT, T].
__global__ __launch_bounds__(64) void k6_fir_scan2(const float* __restrict__ z2ct,
                                                   float* __restrict__ out) {
    const int lane = threadIdx.x;
    const int g = blockIdx.x / NCHUNK;    // bo group 0..4
    const int ck = blockIdx.x % NCHUNK;
    const int tstart = ck * CLEN;
    const int tend = tstart + CLEN;
    const int t0 = (tstart >= 100) ? tstart - 100 : 0;
    const int bo = (g << 6) + lane;       // 0..319
    const float* base = z2ct + (size_t)g * T_SZ * 64 + lane;
    float* op = out + (size_t)bo * T_SZ;
    double A = 0.0, Bs = 0.0, A2 = 0.0, Bs2 = 0.0;
    float ra = 0.0f, rb = 0.0f;
    const double TAIL = D100_D * CS_D;
    float xb[NPF], xdb[NPF];
#pragma unroll
    for (int i = 0; i < NPF; ++i) {
        int t = t0 + i;
        xb[i] = base[(size_t)t * 64];
        int td = t - 100;
        xdb[i] = (td >= 0) ? base[(size_t)td * 64] : 0.0f;
    }
    for (int tb = t0; tb < tend; tb += NPF) {
#pragma unroll
        for (int i = 0; i < NPF; ++i) {
            const int t = tb + i;
            float x = xb[i], xd = xdb[i];
            const int tn = t + NPF;
            xb[i] = (tn < T_SZ) ? base[(size_t)tn * 64] : 0.0f;
            const int td = tn - 100;
            xdb[i] = (td >= 0) ? base[(size_t)td * 64] : 0.0f;
            Bs = DS_D * Bs + DS_D * A;
            A = DS_D * A + (double)x;
            Bs2 = DS_D * Bs2 + DS_D * A2;
            A2 = DS_D * A2 + (double)xd;
            double y = CS_D * Bs - TAIL * (Bs2 + 100.0 * A2);
            float u = (float)y + CREF_F * rb;
            float s = (u >= 10.0f) ? 1.0f : 0.0f;
            float ran = DREF_F * ra + s;
            float rbn = DREF_F * rb + DREF_F * ra;
            ra = ran; rb = rbn;
            if (t >= tstart) op[t] = s;
        }
    }
}

// ---------------------------------------------------------------------------
extern "C" void kernel_launch(void* const* d_in, const int* in_sizes, int n_in,
                              void* d_out, int out_size, void* d_ws, size_t ws_size,
                              hipStream_t stream) {
    const float* spikeInput = (const float*)d_in[0];  // [32, 2312, 350]
    const float* W1 = (const float*)d_in[1];          // [512, 2312]
    const float* W2 = (const float*)d_in[2];          // [10, 512]
    float* out = (float*)d_out;                       // [32, 10, 350]

    char* ws = (char*)d_ws;
    float* W1s = (float*)(ws + 0);                        //  4,737,024 B (2313 rows x 2 halves)
    uint32_t* bits1 = (uint32_t*)(ws + 4737024);          //  3,270,400 B
    float* z1ct = (float*)(ws + 8007424);                 // 22,937,600 B
    // z2ct aliases bits1's region: bits1 is dead after k3, z2ct written by k45.
    float* z2ct = (float*)(ws + 4737024);                 //    448,000 B (alias)
    // total: 30,945,024 B

    k12<<<NW32 * B_SZ + NW32 * 16 + 1, 384, 0, stream>>>(spikeInput, W1, bits1, W1s);
    k3_dense1<<<dim3(B_SZ * T_SZ, 2), 256, 0, stream>>>(bits1, W1s, z1ct);
    k45<<<B_SZ * NCHUNK, 512, 0, stream>>>(z1ct, W2, z2ct);
    k6_fir_scan2<<<5 * NCHUNK, 64, 0, stream>>>(z2ct, out);
}